// Round 1
// baseline (1547.370 us; speedup 1.0000x reference)
//
#include <hip/hip_runtime.h>
#include <math.h>

#define D 64
#define B 64
#define NPB 256   // nodes per block in attention kernels

__device__ __forceinline__ unsigned encf(float x) {
  unsigned u = __float_as_uint(x);
  return (u & 0x80000000u) ? ~u : (u | 0x80000000u);
}
__device__ __forceinline__ float decf(unsigned e) {
  return (e & 0x80000000u) ? __uint_as_float(e ^ 0x80000000u) : __uint_as_float(~e);
}
__device__ __forceinline__ float sigm(float x) { return 1.0f / (1.0f + expf(-x)); }

// ---------------- edge aggregation (scatter-mean of efeat onto dst nodes) ----

__global__ void k_deg(const int* __restrict__ edge_dst, float* __restrict__ deg, int E) {
  int i = blockIdx.x * blockDim.x + threadIdx.x;
  if (i < E) atomicAdd(&deg[edge_dst[i]], 1.0f);
}

__global__ void k_edge_scatter(const float* __restrict__ efeat, const int* __restrict__ edge_dst,
                               float* __restrict__ edge_agg, int E) {
  int idx = blockIdx.x * blockDim.x + threadIdx.x;   // E*16 threads, one float4 each
  int eid = idx >> 4;
  int d4  = idx & 15;
  if (eid >= E) return;
  int dst = edge_dst[eid];
  float4 v = *(const float4*)(efeat + (size_t)eid * D + d4 * 4);
  float* p = edge_agg + (size_t)dst * D + d4 * 4;
  atomicAdd(p + 0, v.x);
  atomicAdd(p + 1, v.y);
  atomicAdd(p + 2, v.z);
  atomicAdd(p + 3, v.w);
}

__global__ void k_edge_div(float* __restrict__ edge_agg, const float* __restrict__ deg, int N) {
  int idx = blockIdx.x * blockDim.x + threadIdx.x;   // N*16 threads
  int n = idx >> 4;
  int d4 = idx & 15;
  if (n >= N) return;
  float inv = 1.0f / fmaxf(deg[n], 1.0f);
  float4* p = (float4*)(edge_agg + (size_t)n * D + d4 * 4);
  float4 v = *p;
  v.x *= inv; v.y *= inv; v.z *= inv; v.w *= inv;
  *p = v;
}

// ---------------- Set2Set pieces ----------------

// One block per graph b, 256 threads (thread j computes gate j).
// Also zeroes per-iteration attention accumulators m_enc/s/r.
__global__ void k_lstm(const float* __restrict__ qstar, float* __restrict__ h, float* __restrict__ c,
                       const float* __restrict__ Wih, const float* __restrict__ Whh,
                       const float* __restrict__ bih, const float* __restrict__ bhh,
                       unsigned* __restrict__ m_enc, float* __restrict__ s_buf,
                       float* __restrict__ r_buf) {
  __shared__ float sq[2 * D], sh[D], sg[4 * D];
  int b = blockIdx.x, j = threadIdx.x;
  if (j < 2 * D) sq[j] = qstar[b * 2 * D + j];
  if (j >= 128 && j < 192) sh[j - 128] = h[b * D + (j - 128)];
  __syncthreads();
  float acc = bih[j] + bhh[j];
  const float* wr = Wih + (size_t)j * (2 * D);
  #pragma unroll 8
  for (int k = 0; k < 2 * D; ++k) acc += sq[k] * wr[k];
  const float* wr2 = Whh + (size_t)j * D;
  #pragma unroll 8
  for (int k = 0; k < D; ++k) acc += sh[k] * wr2[k];
  sg[j] = acc;
  __syncthreads();
  if (j < D) {
    float ig = sigm(sg[j]);
    float fg = sigm(sg[D + j]);
    float gg = tanhf(sg[2 * D + j]);
    float og = sigm(sg[3 * D + j]);
    float cn = fg * c[b * D + j] + ig * gg;
    c[b * D + j] = cn;
    h[b * D + j] = og * tanhf(cn);
    r_buf[b * D + j] = 0.0f;
  }
  if (j == 64) s_buf[b] = 0.0f;
  if (j == 65) m_enc[b] = 0u;   // decodes below any finite float after first real max
}

// e[n] = dot(feat[n], h[gid[n]]); segment max into m_enc (encoded-uint atomicMax).
// 256 threads: 16 nodes per iteration (16 lanes x float4 per node).
__global__ void k_att_logits(const float* __restrict__ feat, const int* __restrict__ gid,
                             const float* __restrict__ h, float* __restrict__ e_buf,
                             unsigned* __restrict__ m_enc, int N) {
  int tid = threadIdx.x;
  int sub = tid >> 4;
  int d4  = tid & 15;
  int base = blockIdx.x * NPB;
  float local_max = -3.4e38f;
  int cur_g = -1;
  for (int it = 0; it < NPB / 16; ++it) {
    int n = base + it * 16 + sub;
    if (n < N) {
      int g = gid[n];
      float4 f  = *(const float4*)(feat + (size_t)n * D + d4 * 4);
      float4 hv = *(const float4*)(h + g * D + d4 * 4);
      float dot = f.x * hv.x + f.y * hv.y + f.z * hv.z + f.w * hv.w;
      dot += __shfl_xor(dot, 1);
      dot += __shfl_xor(dot, 2);
      dot += __shfl_xor(dot, 4);
      dot += __shfl_xor(dot, 8);
      if (d4 == 0) {
        e_buf[n] = dot;
        if (g != cur_g) {
          if (cur_g >= 0) atomicMax(&m_enc[cur_g], encf(local_max));
          cur_g = g;
          local_max = dot;
        } else {
          local_max = fmaxf(local_max, dot);
        }
      }
    }
  }
  if (cur_g >= 0) atomicMax(&m_enc[cur_g], encf(local_max));
}

// ex = exp(e - m[g]); s[g] += ex; r[g][:] += feat[n][:]*ex  (register-local, flush on g change)
__global__ void k_att_accum(const float* __restrict__ feat, const int* __restrict__ gid,
                            const float* __restrict__ e_buf, const unsigned* __restrict__ m_enc,
                            float* __restrict__ s_buf, float* __restrict__ r_buf, int N) {
  int tid = threadIdx.x;
  int sub = tid >> 4;
  int d4  = tid & 15;
  int base = blockIdx.x * NPB;
  float4 acc = make_float4(0.f, 0.f, 0.f, 0.f);
  float sum_ex = 0.0f;
  int cur_g = -1;
  for (int it = 0; it < NPB / 16; ++it) {
    int n = base + it * 16 + sub;
    if (n < N) {
      int g = gid[n];
      if (g != cur_g) {
        if (cur_g >= 0) {
          float* rp = r_buf + cur_g * D + d4 * 4;
          atomicAdd(rp + 0, acc.x);
          atomicAdd(rp + 1, acc.y);
          atomicAdd(rp + 2, acc.z);
          atomicAdd(rp + 3, acc.w);
          if (d4 == 0) atomicAdd(&s_buf[cur_g], sum_ex);
        }
        cur_g = g;
        acc = make_float4(0.f, 0.f, 0.f, 0.f);
        sum_ex = 0.0f;
      }
      float m = decf(m_enc[g]);
      float ex = expf(e_buf[n] - m);
      float4 f = *(const float4*)(feat + (size_t)n * D + d4 * 4);
      acc.x += f.x * ex; acc.y += f.y * ex; acc.z += f.z * ex; acc.w += f.w * ex;
      if (d4 == 0) sum_ex += ex;
    }
  }
  if (cur_g >= 0) {
    float* rp = r_buf + cur_g * D + d4 * 4;
    atomicAdd(rp + 0, acc.x);
    atomicAdd(rp + 1, acc.y);
    atomicAdd(rp + 2, acc.z);
    atomicAdd(rp + 3, acc.w);
    if (d4 == 0) atomicAdd(&s_buf[cur_g], sum_ex);
  }
}

// q_star[b] = [h[b], r[b]/s[b]]
__global__ void k_finalize(const float* __restrict__ h, const float* __restrict__ r_buf,
                           const float* __restrict__ s_buf, float* __restrict__ qstar) {
  int b = blockIdx.x, t = threadIdx.x;   // 64 threads
  float sv = s_buf[b];
  qstar[b * 2 * D + t] = h[b * D + t];
  qstar[b * 2 * D + D + t] = r_buf[b * D + t] / sv;
}

// out[b] = W3 @ relu(W2 @ relu(W1 @ [qn;qe] + b1) + b2) + b3
__global__ void k_mlp(const float* __restrict__ qn, const float* __restrict__ qe,
                      const float* __restrict__ W1, const float* __restrict__ b1,
                      const float* __restrict__ W2, const float* __restrict__ b2,
                      const float* __restrict__ W3, const float* __restrict__ b3,
                      float* __restrict__ out) {
  __shared__ float x[4 * D], h1[32], h2[16];
  int b = blockIdx.x, t = threadIdx.x;   // 128 threads
  x[t] = qn[b * 2 * D + t];
  x[128 + t] = qe[b * 2 * D + t];
  __syncthreads();
  if (t < 32) {
    float acc = b1[t];
    const float* w = W1 + (size_t)t * (4 * D);
    #pragma unroll 8
    for (int k = 0; k < 4 * D; ++k) acc += x[k] * w[k];
    h1[t] = fmaxf(acc, 0.0f);
  }
  __syncthreads();
  if (t < 16) {
    float acc = b2[t];
    const float* w = W2 + (size_t)t * 32;
    #pragma unroll
    for (int k = 0; k < 32; ++k) acc += h1[k] * w[k];
    h2[t] = fmaxf(acc, 0.0f);
  }
  __syncthreads();
  if (t == 0) {
    float acc = b3[0];
    #pragma unroll
    for (int k = 0; k < 16; ++k) acc += h2[k] * W3[k];
    out[b] = acc;
  }
}

// ---------------- driver ----------------

extern "C" void kernel_launch(void* const* d_in, const int* in_sizes, int n_in,
                              void* d_out, int out_size, void* d_ws, size_t ws_size,
                              hipStream_t stream) {
  const float* feat      = (const float*)d_in[0];
  const float* efeat     = (const float*)d_in[1];
  const int*   edge_dst  = (const int*)d_in[2];
  const int*   node_graph= (const int*)d_in[3];
  const float* node_Wih  = (const float*)d_in[5];
  const float* node_Whh  = (const float*)d_in[6];
  const float* node_bih  = (const float*)d_in[7];
  const float* node_bhh  = (const float*)d_in[8];
  const float* edge_Wih  = (const float*)d_in[9];
  const float* edge_Whh  = (const float*)d_in[10];
  const float* edge_bih  = (const float*)d_in[11];
  const float* edge_bhh  = (const float*)d_in[12];
  const float* W1 = (const float*)d_in[13];
  const float* b1 = (const float*)d_in[14];
  const float* W2 = (const float*)d_in[15];
  const float* b2 = (const float*)d_in[16];
  const float* W3 = (const float*)d_in[17];
  const float* b3 = (const float*)d_in[18];
  float* out = (float*)d_out;

  const int N = in_sizes[0] / D;
  const int E = in_sizes[2];

  // ws layout (floats)
  float* ws = (float*)d_ws;
  size_t off = 0;
  float* edge_agg = ws + off; off += (size_t)N * D;   // 6.4M
  float* deg      = ws + off; off += N;               // 100K
  float* e_buf    = ws + off; off += N;               // 100K
  float* h_buf    = ws + off; off += B * D;
  float* c_buf    = ws + off; off += B * D;
  float* q_node   = ws + off; off += B * 2 * D;
  float* q_edge   = ws + off; off += B * 2 * D;
  float* s_buf    = ws + off; off += B;
  float* r_buf    = ws + off; off += B * D;
  unsigned* m_enc = (unsigned*)(ws + off); off += B;

  // zero edge_agg + deg (contiguous), and h,c,q_node,q_edge (contiguous)
  hipMemsetAsync(edge_agg, 0, ((size_t)N * D + N) * sizeof(float), stream);
  hipMemsetAsync(h_buf, 0, (size_t)(B * D * 2 + B * 2 * D * 2) * sizeof(float), stream);

  // edge scatter-mean
  k_deg<<<(E + 255) / 256, 256, 0, stream>>>(edge_dst, deg, E);
  {
    long long tot = (long long)E * 16;
    k_edge_scatter<<<(int)((tot + 255) / 256), 256, 0, stream>>>(efeat, edge_dst, edge_agg, E);
  }
  {
    long long tot = (long long)N * 16;
    k_edge_div<<<(int)((tot + 255) / 256), 256, 0, stream>>>(edge_agg, deg, N);
  }

  const int att_blocks = (N + NPB - 1) / NPB;

  // ---- node set2set ----
  for (int it = 0; it < 3; ++it) {
    k_lstm<<<B, 256, 0, stream>>>(q_node, h_buf, c_buf, node_Wih, node_Whh, node_bih, node_bhh,
                                  m_enc, s_buf, r_buf);
    k_att_logits<<<att_blocks, 256, 0, stream>>>(feat, node_graph, h_buf, e_buf, m_enc, N);
    k_att_accum<<<att_blocks, 256, 0, stream>>>(feat, node_graph, e_buf, m_enc, s_buf, r_buf, N);
    k_finalize<<<B, 64, 0, stream>>>(h_buf, r_buf, s_buf, q_node);
  }

  // ---- edge set2set ---- (reset LSTM state)
  hipMemsetAsync(h_buf, 0, (size_t)(2 * B * D) * sizeof(float), stream);
  for (int it = 0; it < 3; ++it) {
    k_lstm<<<B, 256, 0, stream>>>(q_edge, h_buf, c_buf, edge_Wih, edge_Whh, edge_bih, edge_bhh,
                                  m_enc, s_buf, r_buf);
    k_att_logits<<<att_blocks, 256, 0, stream>>>(edge_agg, node_graph, h_buf, e_buf, m_enc, N);
    k_att_accum<<<att_blocks, 256, 0, stream>>>(edge_agg, node_graph, e_buf, m_enc, s_buf, r_buf, N);
    k_finalize<<<B, 64, 0, stream>>>(h_buf, r_buf, s_buf, q_edge);
  }

  // ---- final MLP ----
  k_mlp<<<B, 128, 0, stream>>>(q_node, q_edge, W1, b1, W2, b2, W3, b3, out);
}

// Round 2
// 796.489 us; speedup vs baseline: 1.9427x; 1.9427x over previous
//
#include <hip/hip_runtime.h>
#include <math.h>

#define D 64
#define B 64
#define NPB 256      // nodes per block in attention kernels
#define SCAN_BS 1024

__device__ __forceinline__ unsigned encf(float x) {
  unsigned u = __float_as_uint(x);
  return (u & 0x80000000u) ? ~u : (u | 0x80000000u);
}
__device__ __forceinline__ float decf(unsigned e) {
  return (e & 0x80000000u) ? __uint_as_float(e ^ 0x80000000u) : __uint_as_float(~e);
}
__device__ __forceinline__ float sigm(float x) { return 1.0f / (1.0f + expf(-x)); }

// ---------------- CSR build + gather (scatter-mean of efeat onto dst nodes) --

__global__ void k_deg(const int* __restrict__ edge_dst, int* __restrict__ deg, int E) {
  int i = blockIdx.x * blockDim.x + threadIdx.x;
  if (i < E) atomicAdd(&deg[edge_dst[i]], 1);
}

// exclusive scan, stage 1: per-block Hillis-Steele; writes exclusive partials
// into row_start and the block total into blocksum.
__global__ void k_scan1(const int* __restrict__ deg, int* __restrict__ row_start,
                        int* __restrict__ blocksum, int N) {
  __shared__ int sm[SCAN_BS];
  int t = threadIdx.x;
  int base = blockIdx.x * SCAN_BS;
  int v = (base + t < N) ? deg[base + t] : 0;
  sm[t] = v;
  __syncthreads();
  for (int ofs = 1; ofs < SCAN_BS; ofs <<= 1) {
    int add = (t >= ofs) ? sm[t - ofs] : 0;
    __syncthreads();
    sm[t] += add;
    __syncthreads();
  }
  if (base + t < N) row_start[base + t] = sm[t] - v;   // exclusive
  if (t == SCAN_BS - 1) blocksum[blockIdx.x] = sm[t];
}

// stage 2: one block scans the (<=128) block sums -> exclusive block offsets
__global__ void k_scan2(int* __restrict__ blocksum, int nb) {
  __shared__ int sm[128];
  int t = threadIdx.x;
  int v = (t < nb) ? blocksum[t] : 0;
  sm[t] = v;
  __syncthreads();
  for (int ofs = 1; ofs < 128; ofs <<= 1) {
    int add = (t >= ofs) ? sm[t - ofs] : 0;
    __syncthreads();
    sm[t] += add;
    __syncthreads();
  }
  if (t < nb) blocksum[t] = sm[t] - v;   // exclusive, in place
}

// stage 3: add block offsets in place; copy to cursor
__global__ void k_scan3(int* __restrict__ row_start, const int* __restrict__ blocksum,
                        int* __restrict__ cursor, int N) {
  int n = blockIdx.x * blockDim.x + threadIdx.x;
  if (n < N) {
    int v = row_start[n] + blocksum[n / SCAN_BS];
    row_start[n] = v;
    cursor[n] = v;
  }
}

__global__ void k_fill(const int* __restrict__ edge_dst, int* __restrict__ cursor,
                       int* __restrict__ csr, int E) {
  int e = blockIdx.x * blockDim.x + threadIdx.x;
  if (e < E) {
    int dst = edge_dst[e];
    int idx = atomicAdd(&cursor[dst], 1);
    csr[idx] = e;
  }
}

// one 64-lane wave per node; lane = feature dim. Each edge row read is one
// fully-coalesced 256B transaction. No atomics.
__global__ void k_gather(const float* __restrict__ efeat, const int* __restrict__ csr,
                         const int* __restrict__ row_start, const int* __restrict__ deg,
                         float* __restrict__ edge_agg, int N) {
  int wave = (blockIdx.x * blockDim.x + threadIdx.x) >> 6;
  int lane = threadIdx.x & 63;
  if (wave >= N) return;
  int base = row_start[wave];
  int dg = deg[wave];
  float acc = 0.0f;
  for (int i = 0; i < dg; ++i) {
    int e = csr[base + i];                      // wave-uniform load
    acc += efeat[(size_t)e * D + lane];         // coalesced 256B row
  }
  edge_agg[(size_t)wave * D + lane] = acc / fmaxf((float)dg, 1.0f);
}

// ---------------- Set2Set pieces ----------------

// One block per graph b, 256 threads (thread j computes gate j).
// Also zeroes per-iteration attention accumulators m_enc/s/r.
__global__ void k_lstm(const float* __restrict__ qstar, float* __restrict__ h, float* __restrict__ c,
                       const float* __restrict__ Wih, const float* __restrict__ Whh,
                       const float* __restrict__ bih, const float* __restrict__ bhh,
                       unsigned* __restrict__ m_enc, float* __restrict__ s_buf,
                       float* __restrict__ r_buf) {
  __shared__ float sq[2 * D], sh[D], sg[4 * D];
  int b = blockIdx.x, j = threadIdx.x;
  if (j < 2 * D) sq[j] = qstar[b * 2 * D + j];
  if (j >= 128 && j < 192) sh[j - 128] = h[b * D + (j - 128)];
  __syncthreads();
  float acc = bih[j] + bhh[j];
  const float* wr = Wih + (size_t)j * (2 * D);
  #pragma unroll 8
  for (int k = 0; k < 2 * D; ++k) acc += sq[k] * wr[k];
  const float* wr2 = Whh + (size_t)j * D;
  #pragma unroll 8
  for (int k = 0; k < D; ++k) acc += sh[k] * wr2[k];
  sg[j] = acc;
  __syncthreads();
  if (j < D) {
    float ig = sigm(sg[j]);
    float fg = sigm(sg[D + j]);
    float gg = tanhf(sg[2 * D + j]);
    float og = sigm(sg[3 * D + j]);
    float cn = fg * c[b * D + j] + ig * gg;
    c[b * D + j] = cn;
    h[b * D + j] = og * tanhf(cn);
    r_buf[b * D + j] = 0.0f;
  }
  if (j == 64) s_buf[b] = 0.0f;
  if (j == 65) m_enc[b] = 0u;   // decodes below any finite float
}

// e[n] = dot(feat[n], h[gid[n]]); segment max into m_enc (encoded-uint atomicMax).
__global__ void k_att_logits(const float* __restrict__ feat, const int* __restrict__ gid,
                             const float* __restrict__ h, float* __restrict__ e_buf,
                             unsigned* __restrict__ m_enc, int N) {
  int tid = threadIdx.x;
  int sub = tid >> 4;
  int d4  = tid & 15;
  int base = blockIdx.x * NPB;
  float local_max = -3.4e38f;
  int cur_g = -1;
  for (int it = 0; it < NPB / 16; ++it) {
    int n = base + it * 16 + sub;
    if (n < N) {
      int g = gid[n];
      float4 f  = *(const float4*)(feat + (size_t)n * D + d4 * 4);
      float4 hv = *(const float4*)(h + g * D + d4 * 4);
      float dot = f.x * hv.x + f.y * hv.y + f.z * hv.z + f.w * hv.w;
      dot += __shfl_xor(dot, 1);
      dot += __shfl_xor(dot, 2);
      dot += __shfl_xor(dot, 4);
      dot += __shfl_xor(dot, 8);
      if (d4 == 0) {
        e_buf[n] = dot;
        if (g != cur_g) {
          if (cur_g >= 0) atomicMax(&m_enc[cur_g], encf(local_max));
          cur_g = g;
          local_max = dot;
        } else {
          local_max = fmaxf(local_max, dot);
        }
      }
    }
  }
  if (cur_g >= 0) atomicMax(&m_enc[cur_g], encf(local_max));
}

// ex = exp(e - m[g]); s[g] += ex; r[g][:] += feat[n][:]*ex  (register-local, flush on g change)
__global__ void k_att_accum(const float* __restrict__ feat, const int* __restrict__ gid,
                            const float* __restrict__ e_buf, const unsigned* __restrict__ m_enc,
                            float* __restrict__ s_buf, float* __restrict__ r_buf, int N) {
  int tid = threadIdx.x;
  int sub = tid >> 4;
  int d4  = tid & 15;
  int base = blockIdx.x * NPB;
  float4 acc = make_float4(0.f, 0.f, 0.f, 0.f);
  float sum_ex = 0.0f;
  int cur_g = -1;
  for (int it = 0; it < NPB / 16; ++it) {
    int n = base + it * 16 + sub;
    if (n < N) {
      int g = gid[n];
      if (g != cur_g) {
        if (cur_g >= 0) {
          float* rp = r_buf + cur_g * D + d4 * 4;
          atomicAdd(rp + 0, acc.x);
          atomicAdd(rp + 1, acc.y);
          atomicAdd(rp + 2, acc.z);
          atomicAdd(rp + 3, acc.w);
          if (d4 == 0) atomicAdd(&s_buf[cur_g], sum_ex);
        }
        cur_g = g;
        acc = make_float4(0.f, 0.f, 0.f, 0.f);
        sum_ex = 0.0f;
      }
      float m = decf(m_enc[g]);
      float ex = expf(e_buf[n] - m);
      float4 f = *(const float4*)(feat + (size_t)n * D + d4 * 4);
      acc.x += f.x * ex; acc.y += f.y * ex; acc.z += f.z * ex; acc.w += f.w * ex;
      if (d4 == 0) sum_ex += ex;
    }
  }
  if (cur_g >= 0) {
    float* rp = r_buf + cur_g * D + d4 * 4;
    atomicAdd(rp + 0, acc.x);
    atomicAdd(rp + 1, acc.y);
    atomicAdd(rp + 2, acc.z);
    atomicAdd(rp + 3, acc.w);
    if (d4 == 0) atomicAdd(&s_buf[cur_g], sum_ex);
  }
}

// q_star[b] = [h[b], r[b]/s[b]]
__global__ void k_finalize(const float* __restrict__ h, const float* __restrict__ r_buf,
                           const float* __restrict__ s_buf, float* __restrict__ qstar) {
  int b = blockIdx.x, t = threadIdx.x;   // 64 threads
  float sv = s_buf[b];
  qstar[b * 2 * D + t] = h[b * D + t];
  qstar[b * 2 * D + D + t] = r_buf[b * D + t] / sv;
}

// out[b] = W3 @ relu(W2 @ relu(W1 @ [qn;qe] + b1) + b2) + b3
__global__ void k_mlp(const float* __restrict__ qn, const float* __restrict__ qe,
                      const float* __restrict__ W1, const float* __restrict__ b1,
                      const float* __restrict__ W2, const float* __restrict__ b2,
                      const float* __restrict__ W3, const float* __restrict__ b3,
                      float* __restrict__ out) {
  __shared__ float x[4 * D], h1[32], h2[16];
  int b = blockIdx.x, t = threadIdx.x;   // 128 threads
  x[t] = qn[b * 2 * D + t];
  x[128 + t] = qe[b * 2 * D + t];
  __syncthreads();
  if (t < 32) {
    float acc = b1[t];
    const float* w = W1 + (size_t)t * (4 * D);
    #pragma unroll 8
    for (int k = 0; k < 4 * D; ++k) acc += x[k] * w[k];
    h1[t] = fmaxf(acc, 0.0f);
  }
  __syncthreads();
  if (t < 16) {
    float acc = b2[t];
    const float* w = W2 + (size_t)t * 32;
    #pragma unroll
    for (int k = 0; k < 32; ++k) acc += h1[k] * w[k];
    h2[t] = fmaxf(acc, 0.0f);
  }
  __syncthreads();
  if (t == 0) {
    float acc = b3[0];
    #pragma unroll
    for (int k = 0; k < 16; ++k) acc += h2[k] * W3[k];
    out[b] = acc;
  }
}

// ---------------- driver ----------------

extern "C" void kernel_launch(void* const* d_in, const int* in_sizes, int n_in,
                              void* d_out, int out_size, void* d_ws, size_t ws_size,
                              hipStream_t stream) {
  const float* feat      = (const float*)d_in[0];
  const float* efeat     = (const float*)d_in[1];
  const int*   edge_dst  = (const int*)d_in[2];
  const int*   node_graph= (const int*)d_in[3];
  const float* node_Wih  = (const float*)d_in[5];
  const float* node_Whh  = (const float*)d_in[6];
  const float* node_bih  = (const float*)d_in[7];
  const float* node_bhh  = (const float*)d_in[8];
  const float* edge_Wih  = (const float*)d_in[9];
  const float* edge_Whh  = (const float*)d_in[10];
  const float* edge_bih  = (const float*)d_in[11];
  const float* edge_bhh  = (const float*)d_in[12];
  const float* W1 = (const float*)d_in[13];
  const float* b1 = (const float*)d_in[14];
  const float* W2 = (const float*)d_in[15];
  const float* b2 = (const float*)d_in[16];
  const float* W3 = (const float*)d_in[17];
  const float* b3 = (const float*)d_in[18];
  float* out = (float*)d_out;

  const int N = in_sizes[0] / D;
  const int E = in_sizes[2];

  // ws layout
  float* ws = (float*)d_ws;
  size_t off = 0;
  float* edge_agg = ws + off; off += (size_t)N * D;       // 25.6 MB
  float* e_buf    = ws + off; off += N;
  float* h_buf    = ws + off; off += B * D;
  float* c_buf    = ws + off; off += B * D;
  float* q_node   = ws + off; off += B * 2 * D;
  float* q_edge   = ws + off; off += B * 2 * D;
  float* s_buf    = ws + off; off += B;
  float* r_buf    = ws + off; off += B * D;
  unsigned* m_enc = (unsigned*)(ws + off); off += B;
  int* deg        = (int*)(ws + off); off += N;
  int* row_start  = (int*)(ws + off); off += N;
  int* cursor     = (int*)(ws + off); off += N;
  int* blocksum   = (int*)(ws + off); off += 128;
  int* csr        = (int*)(ws + off); off += E;           // 4 MB

  // zero deg; zero h,c,q_node,q_edge (contiguous)
  hipMemsetAsync(deg, 0, (size_t)N * sizeof(int), stream);
  hipMemsetAsync(h_buf, 0, (size_t)(B * D * 2 + B * 2 * D * 2) * sizeof(float), stream);

  // CSR build
  const int nb = (N + SCAN_BS - 1) / SCAN_BS;
  k_deg<<<(E + 255) / 256, 256, 0, stream>>>(edge_dst, deg, E);
  k_scan1<<<nb, SCAN_BS, 0, stream>>>(deg, row_start, blocksum, N);
  k_scan2<<<1, 128, 0, stream>>>(blocksum, nb);
  k_scan3<<<(N + 255) / 256, 256, 0, stream>>>(row_start, blocksum, cursor, N);
  k_fill<<<(E + 255) / 256, 256, 0, stream>>>(edge_dst, cursor, csr, E);

  // gather: one wave per node, 4 waves per block
  k_gather<<<(N + 3) / 4, 256, 0, stream>>>(efeat, csr, row_start, deg, edge_agg, N);

  const int att_blocks = (N + NPB - 1) / NPB;

  // ---- node set2set ----
  for (int it = 0; it < 3; ++it) {
    k_lstm<<<B, 256, 0, stream>>>(q_node, h_buf, c_buf, node_Wih, node_Whh, node_bih, node_bhh,
                                  m_enc, s_buf, r_buf);
    k_att_logits<<<att_blocks, 256, 0, stream>>>(feat, node_graph, h_buf, e_buf, m_enc, N);
    k_att_accum<<<att_blocks, 256, 0, stream>>>(feat, node_graph, e_buf, m_enc, s_buf, r_buf, N);
    k_finalize<<<B, 64, 0, stream>>>(h_buf, r_buf, s_buf, q_node);
  }

  // ---- edge set2set ---- (reset LSTM state)
  hipMemsetAsync(h_buf, 0, (size_t)(2 * B * D) * sizeof(float), stream);
  for (int it = 0; it < 3; ++it) {
    k_lstm<<<B, 256, 0, stream>>>(q_edge, h_buf, c_buf, edge_Wih, edge_Whh, edge_bih, edge_bhh,
                                  m_enc, s_buf, r_buf);
    k_att_logits<<<att_blocks, 256, 0, stream>>>(edge_agg, node_graph, h_buf, e_buf, m_enc, N);
    k_att_accum<<<att_blocks, 256, 0, stream>>>(edge_agg, node_graph, e_buf, m_enc, s_buf, r_buf, N);
    k_finalize<<<B, 64, 0, stream>>>(h_buf, r_buf, s_buf, q_edge);
  }

  // ---- final MLP ----
  k_mlp<<<B, 128, 0, stream>>>(q_node, q_edge, W1, b1, W2, b2, W3, b3, out);
}